// Round 1
// 858.889 us; speedup vs baseline: 2.1345x; 2.1345x over previous
//
#include <hip/hip_runtime.h>

#define NUM_CAT 16
#define NUM_ATTR 144
#define NUM_NUM 128
#define N_ARY 32
#define NUM_SEG 100000
#define N_ROWS 1000000

// ws layout:
//   int   hdr_i[0..31]  : selcol[j] = 16 + top_num_idx[j] (full-row column)
//   float hdr_f[32..63] : conf[j]
//   int   hdr_i[64]     : topcat (argmax of cat_mask)
//   byte offset 512     : float agg[NUM_SEG*32]  (12.8 MB)
#define AGG_OFFSET 512

// One block of 128 threads. No scratch arrays (rule #20: runtime-indexed
// per-thread arrays spill to local memory ~300cy/access — the old serial
// top-32 scan burned 2.4M cycles on exactly that). Top-32 selection is
// done as a parallel rank computation over LDS broadcasts.
__global__ void setup_kernel(const float* __restrict__ cat_mask,
                             const float* __restrict__ num_mask,
                             int* __restrict__ hdr_i,
                             float* __restrict__ hdr_f) {
    __shared__ float s_cm[NUM_CAT];
    __shared__ float s_x[NUM_NUM];
    __shared__ float s_p[NUM_NUM];
    const int tid = threadIdx.x;            // 0..127

    if (tid < NUM_CAT) s_cm[tid] = cat_mask[tid];
    float x = num_mask[tid];
    s_x[tid] = x;
    __syncthreads();

    // --- numeric softmax (redundant per-thread reduce; LDS same-addr reads
    //     broadcast, so the 128-iter loops are a few hundred cycles total) ---
    float nmax = s_x[0];
    #pragma unroll 8
    for (int i = 1; i < NUM_NUM; ++i) nmax = fmaxf(nmax, s_x[i]);
    float e = expf(x - nmax);
    s_p[tid] = e;
    __syncthreads();
    float nsum = 0.f;
    #pragma unroll 8
    for (int i = 0; i < NUM_NUM; ++i) nsum += s_p[i];   // index order == old serial sum
    float inv = 1.0f / nsum;
    float p = e * inv;                                   // == cm value JAX ranks on
    __syncthreads();
    s_p[tid] = p;                                        // normalized probs for ranking
    __syncthreads();

    // --- cat softmax top-1 (redundant on all threads; 16 elems, registers only) ---
    float cmax = s_cm[0]; int cidx = 0;
    #pragma unroll
    for (int i = 1; i < NUM_CAT; ++i) {
        float v = s_cm[i];
        if (v > cmax) { cmax = v; cidx = i; }   // strict > : ties -> lower idx
    }
    float csum = 0.f;
    #pragma unroll
    for (int i = 0; i < NUM_CAT; ++i) csum += expf(s_cm[i] - cmax);
    float top_cat_val = 1.0f / csum;            // exp(0)/sum

    // --- rank of this thread's prob among all 128 (descending, stable) ---
    int rank = 0;
    #pragma unroll 8
    for (int j = 0; j < NUM_NUM; ++j) {
        float pj = s_p[j];
        rank += (pj > p) || (pj == p && j < tid);
    }
    if (rank < N_ARY) {
        hdr_i[rank] = NUM_CAT + tid;                     // column in full input row
        hdr_f[32 + rank] = 0.5f * (p + top_cat_val);     // conf[rank]
    }
    if (tid == 0) hdr_i[64] = cidx;
}

__global__ void accum_kernel(const float* __restrict__ inputs,
                             const int* __restrict__ idx,
                             const int* __restrict__ hdr_i,
                             float* __restrict__ agg) {
    const int j = threadIdx.x & 31;          // invariant: stride % 32 == 0
    const int col = hdr_i[j];
    const int topcat = hdr_i[64];
    const int total = N_ROWS * 32;
    int t = blockIdx.x * blockDim.x + threadIdx.x;
    const int stride = gridDim.x * blockDim.x;
    for (; t < total; t += stride) {
        int row = t >> 5;
        int seg = idx[row * NUM_CAT + topcat];
        float v = inputs[row * NUM_ATTR + col];
        atomicAdd(&agg[seg * 32 + j], v);
    }
}

__global__ void gather_kernel(const int* __restrict__ idx,
                              const int* __restrict__ hdr_i,
                              const float* __restrict__ hdr_f,
                              const float* __restrict__ agg,
                              float* __restrict__ out) {
    const int j = threadIdx.x & 31;
    const float cf = hdr_f[32 + j];
    const int topcat = hdr_i[64];
    const int total = N_ROWS * 32;
    int t = blockIdx.x * blockDim.x + threadIdx.x;
    const int stride = gridDim.x * blockDim.x;
    for (; t < total; t += stride) {
        int row = t >> 5;
        int seg = idx[row * NUM_CAT + topcat];
        out[t] = agg[seg * 32 + j] * cf;
    }
}

extern "C" void kernel_launch(void* const* d_in, const int* in_sizes, int n_in,
                              void* d_out, int out_size, void* d_ws, size_t ws_size,
                              hipStream_t stream) {
    const float* inputs   = (const float*)d_in[0];   // (1M, 144) f32
    const int*   idx      = (const int*)d_in[1];     // (1M, 16) int
    const float* cat_mask = (const float*)d_in[2];   // (16,)
    const float* num_mask = (const float*)d_in[3];   // (128,)
    float* out = (float*)d_out;                      // (1M, 32) f32

    int*   hdr_i = (int*)d_ws;
    float* hdr_f = (float*)d_ws;
    float* agg   = (float*)((char*)d_ws + AGG_OFFSET);

    // 1) mask math -> header (parallel rank-based top-k, one 128-thread block)
    setup_kernel<<<1, 128, 0, stream>>>(cat_mask, num_mask, hdr_i, hdr_f);

    // 2) zero agg (memset node is graph-capture safe)
    hipMemsetAsync(agg, 0, (size_t)NUM_SEG * 32 * sizeof(float), stream);

    // 3) segment-sum of the 32 selected columns
    accum_kernel<<<8192, 256, 0, stream>>>(inputs, idx, hdr_i, agg);

    // 4) gather + scale
    gather_kernel<<<8192, 256, 0, stream>>>(idx, hdr_i, hdr_f, agg, out);
}